// Round 6
// baseline (355.373 us; speedup 1.0000x reference)
//
#include <hip/hip_runtime.h>
#include <math.h>

#define T_LEN 2048
#define BSZ 2
#define EMB 1024
#define NHEAD 16
#define HDIM 64
#define QK_LD 2048   // q,k packed [T*B, 2E]

typedef __attribute__((ext_vector_type(8))) short short8v;   // 8 bf16 (4 VGPRs)
typedef __attribute__((ext_vector_type(4))) float floatx4;   // MFMA C/D

__device__ __forceinline__ short f2bf(float f) {
    unsigned u = __float_as_uint(f);
    u += 0x7fffu + ((u >> 16) & 1u);   // RNE
    return (short)(u >> 16);
}

// ---------------------------------------------------------------------------
__global__ __launch_bounds__(256) void f32_to_bf16_k(const float* __restrict__ src,
                                                     short* __restrict__ dst, int n) {
    int i = (blockIdx.x * 256 + threadIdx.x) * 4;
    if (i >= n) return;
    float4 v = *(const float4*)(src + i);
    short4 o = make_short4(f2bf(v.x), f2bf(v.y), f2bf(v.z), f2bf(v.w));
    *(short4*)(dst + i) = o;
}

// ---------------------------------------------------------------------------
// C = A[M,K]*B[N,K]^T + bias; cols < scale_cols get *0.125 (q scale).
// If vTout != 0, cols >= 2*EMB are written TRANSPOSED to vT[b][e][t] (bf16).
// bf16 MFMA 16x16x32, 128x128 tile, BK=32, 4 waves (2x2), 4x4 frags/wave.
// ---------------------------------------------------------------------------
__global__ __launch_bounds__(256) void gemm_bf16(const short* __restrict__ A,
        const short* __restrict__ B, const float* __restrict__ bias,
        void* __restrict__ Cout, short* __restrict__ vTout,
        int M, int N, int K, int scale_cols, int out_bf16, int ldC) {
    __shared__ short As[128][32];
    __shared__ short Bs[128][32];
    const int tid = threadIdx.x;
    const int m0 = blockIdx.y * 128, n0 = blockIdx.x * 128;
    const int lane = tid & 63, w = tid >> 6;
    const int q = lane >> 4, r = lane & 15;
    const int wr = w >> 1, wc = w & 1;
    const int srow = tid >> 2, sc4 = tid & 3;
    const int sp = (sc4 ^ ((srow >> 1) & 3)) * 8;

    const short* Arow0 = A + (size_t)(m0 + srow) * K + sc4 * 8;
    const short* Arow1 = Arow0 + (size_t)64 * K;
    const short* Brow0 = B + (size_t)(n0 + srow) * K + sc4 * 8;
    const short* Brow1 = Brow0 + (size_t)64 * K;

    floatx4 acc[4][4];
    #pragma unroll
    for (int a = 0; a < 4; ++a)
        #pragma unroll
        for (int b2 = 0; b2 < 4; ++b2)
            #pragma unroll
            for (int e = 0; e < 4; ++e) acc[a][b2][e] = 0.f;

    for (int k0 = 0; k0 < K; k0 += 32) {
        int4 a0 = *(const int4*)(Arow0 + k0);
        int4 a1 = *(const int4*)(Arow1 + k0);
        int4 b0 = *(const int4*)(Brow0 + k0);
        int4 b1 = *(const int4*)(Brow1 + k0);
        __syncthreads();
        *(int4*)&As[srow][sp] = a0;
        *(int4*)&As[64 + srow][sp] = a1;
        *(int4*)&Bs[srow][sp] = b0;
        *(int4*)&Bs[64 + srow][sp] = b1;
        __syncthreads();
        short8v af[4], bfr[4];
        #pragma unroll
        for (int mb = 0; mb < 4; ++mb) {
            int row = wr * 64 + mb * 16 + r;
            af[mb] = *(const short8v*)&As[row][(q ^ ((row >> 1) & 3)) * 8];
        }
        #pragma unroll
        for (int nb = 0; nb < 4; ++nb) {
            int row = wc * 64 + nb * 16 + r;
            bfr[nb] = *(const short8v*)&Bs[row][(q ^ ((row >> 1) & 3)) * 8];
        }
        #pragma unroll
        for (int mb = 0; mb < 4; ++mb)
            #pragma unroll
            for (int nb = 0; nb < 4; ++nb)
                acc[mb][nb] = __builtin_amdgcn_mfma_f32_16x16x32_bf16(af[mb], bfr[nb], acc[mb][nb], 0, 0, 0);
    }

    #pragma unroll
    for (int nb = 0; nb < 4; ++nb) {
        const int col = n0 + wc * 64 + nb * 16 + r;
        const float bi = bias[col];
        const float sc = (col < scale_cols) ? 0.125f : 1.0f;
        if (vTout && col >= 2 * EMB) {
            const int e = col - 2 * EMB;
            #pragma unroll
            for (int mb = 0; mb < 4; ++mb) {
                const int base = m0 + wr * 64 + mb * 16 + q * 4;   // multiple of 4
                float v0 = acc[mb][nb][0] + bi, v1 = acc[mb][nb][1] + bi;
                float v2 = acc[mb][nb][2] + bi, v3 = acc[mb][nb][3] + bi;
                // rows (t*2+b): i=0,2 -> b=0 t,t+1 ; i=1,3 -> b=1 t,t+1
                unsigned lo = (unsigned short)f2bf(v0) | ((unsigned)(unsigned short)f2bf(v2) << 16);
                unsigned hi = (unsigned short)f2bf(v1) | ((unsigned)(unsigned short)f2bf(v3) << 16);
                *(unsigned*)&vTout[(size_t)e * T_LEN + (base >> 1)]         = lo;
                *(unsigned*)&vTout[((size_t)EMB + e) * T_LEN + (base >> 1)] = hi;
            }
        } else {
            #pragma unroll
            for (int mb = 0; mb < 4; ++mb)
                #pragma unroll
                for (int i = 0; i < 4; ++i) {
                    const int rowg = m0 + wr * 64 + mb * 16 + q * 4 + i;
                    const float v = (acc[mb][nb][i] + bi) * sc;
                    if (out_bf16) ((short*)Cout)[(size_t)rowg * ldC + col] = f2bf(v);
                    else          ((float*)Cout)[(size_t)rowg * ldC + col] = v;
                }
        }
    }
}

// ---------------------------------------------------------------------------
// Flash causal attention. Triangle load balance WITHOUT atomics: block
// (pairi, bh) processes ttile=pairi then ttile=31-pairi -> every block does
// exactly 33 s-tiles. 512 uniform blocks. K-loop processes 2 s-tiles per
// staging round (3 barriers / 32 MFMA per wave vs 3/16 before), P double-
// buffered. No online max (scores provably small). All LDS reads swizzled.
// ---------------------------------------------------------------------------
__global__ __launch_bounds__(256) void flash_fwd(const short* __restrict__ qk,
        const short* __restrict__ vT, short* __restrict__ ctx,
        float* __restrict__ Lr) {
    __shared__ short Ks[128][64];       // 2 s-tiles of K
    __shared__ short Vt[64][128];       // V^T: [d][2 s-tiles]
    __shared__ short Ps[2][64][64];     // P dbuf; Ps[0] doubles as Q staging
    __shared__ float Lred[4][64];
    const int tid = threadIdx.x;
    const int pairi = blockIdx.x;       // 0..15
    const int bh = blockIdx.y, b = bh >> 4, h = bh & 15;
    const int lane = tid & 63, w = tid >> 6;
    const int q = lane >> 4, r = lane & 15;
    const int RS = BSZ * QK_LD;

    const short* qbase = qk + (size_t)b * QK_LD + h * HDIM;
    const short* kbase = qbase + EMB;
    const short* vbase = vT + ((size_t)b * EMB + h * HDIM) * T_LEN;

    for (int pass = 0; pass < 2; ++pass) {
        const int tt = pass ? (31 - pairi) : pairi;
        const int t0 = tt << 6;
        __syncthreads();   // prior pass's Ps/Lred reads done
        {   // stage Q into Ps[0]
            const int sr = tid >> 3, c8 = tid & 7;
            *(int4*)&Ps[0][sr][(c8 ^ (sr & 7)) * 8] =
                *(const int4*)(qbase + (size_t)(t0 + sr) * RS + c8 * 8);
            *(int4*)&Ps[0][sr + 32][(c8 ^ ((sr + 32) & 7)) * 8] =
                *(const int4*)(qbase + (size_t)(t0 + sr + 32) * RS + c8 * 8);
        }
        __syncthreads();
        short8v qf[4][2];
        #pragma unroll
        for (int mb = 0; mb < 4; ++mb)
            #pragma unroll
            for (int ks = 0; ks < 2; ++ks) {
                int row = mb * 16 + r;
                qf[mb][ks] = *(const short8v*)&Ps[0][row][((ks * 4 + q) ^ (row & 7)) * 8];
            }

        float l_part[4][4];
        floatx4 o[4];
        #pragma unroll
        for (int mb = 0; mb < 4; ++mb)
            #pragma unroll
            for (int i = 0; i < 4; ++i) l_part[mb][i] = 0.f;
        #pragma unroll
        for (int nb = 0; nb < 4; ++nb)
            #pragma unroll
            for (int e = 0; e < 4; ++e) o[nb][e] = 0.f;

        const int ntiles = tt + 1;
        int s2 = 0;
        for (; s2 + 2 <= ntiles; s2 += 2) {   // paired rounds: 128 s per stage
            __syncthreads();
            {   // K: 128 rows x 8 chunks (4 int4/thread)
                const int sr = tid >> 1, cb = (tid & 1) * 4;
                const short* kp = kbase + (size_t)(s2 * 64 + sr) * RS;
                #pragma unroll
                for (int u = 0; u < 4; ++u) {
                    const int c = cb + u;
                    *(int4*)&Ks[sr][(c ^ (sr & 7)) * 8] = *(const int4*)(kp + c * 8);
                }
                // V^T: 64 rows x 16 chunks (4 int4/thread)
                const int vr = tid >> 2, vb0 = (tid & 3) * 4;
                const short* vp = vbase + (size_t)vr * T_LEN + s2 * 64;
                #pragma unroll
                for (int u = 0; u < 4; ++u) {
                    const int c = vb0 + u;
                    const int pc = (c & 8) | ((c & 7) ^ (vr & 7));
                    *(int4*)&Vt[vr][pc * 8] = *(const int4*)(vp + c * 8);
                }
            }
            __syncthreads();
            #pragma unroll
            for (int t2 = 0; t2 < 2; ++t2) {   // QK + P for both tiles
                floatx4 sf[4];
                #pragma unroll
                for (int mb = 0; mb < 4; ++mb)
                    #pragma unroll
                    for (int e = 0; e < 4; ++e) sf[mb][e] = 0.f;
                #pragma unroll
                for (int ks = 0; ks < 2; ++ks) {
                    const int krow = t2 * 64 + w * 16 + r;
                    short8v kf = *(const short8v*)&Ks[krow][((ks * 4 + q) ^ (krow & 7)) * 8];
                    #pragma unroll
                    for (int mb = 0; mb < 4; ++mb)
                        sf[mb] = __builtin_amdgcn_mfma_f32_16x16x32_bf16(qf[mb][ks], kf, sf[mb], 0, 0, 0);
                }
                const bool diag = (s2 + t2 == tt);
                #pragma unroll
                for (int mb = 0; mb < 4; ++mb)
                    #pragma unroll
                    for (int i = 0; i < 4; ++i) {
                        const int rl = mb * 16 + q * 4 + i;
                        float p = (diag && (w * 16 + r > rl)) ? 0.f : __expf(sf[mb][i]);
                        l_part[mb][i] += p;
                        const int c = (w * 2 + (r >> 3)) ^ (rl & 7);
                        Ps[t2][rl][c * 8 + (r & 7)] = f2bf(p);
                    }
            }
            __syncthreads();
            #pragma unroll
            for (int ks = 0; ks < 2; ++ks) {   // PV both s-halves
                const int prow = w * 16 + r;
                const int pcp = ((ks * 4 + q) ^ (prow & 7)) * 8;
                short8v pfA = *(const short8v*)&Ps[0][prow][pcp];
                short8v pfB = *(const short8v*)&Ps[1][prow][pcp];
                #pragma unroll
                for (int nb = 0; nb < 4; ++nb) {
                    const int vrow = nb * 16 + r;
                    const int pcv = (ks * 4 + q) ^ (vrow & 7);
                    short8v vfA = *(const short8v*)&Vt[vrow][pcv * 8];
                    short8v vfB = *(const short8v*)&Vt[vrow][(8 | pcv) * 8];
                    o[nb] = __builtin_amdgcn_mfma_f32_16x16x32_bf16(pfA, vfA, o[nb], 0, 0, 0);
                    o[nb] = __builtin_amdgcn_mfma_f32_16x16x32_bf16(pfB, vfB, o[nb], 0, 0, 0);
                }
            }
        }
        if (s2 < ntiles) {   // odd tail: single tile s2 == tt (diagonal)
            __syncthreads();
            {   // 64 rows x 8 chunks each (2 int4/thread)
                const int sr = tid >> 2, cb = (tid & 3) * 2;
                const short* kp = kbase + (size_t)(s2 * 64 + sr) * RS;
                const short* vp = vbase + (size_t)sr * T_LEN + s2 * 64;
                #pragma unroll
                for (int u = 0; u < 2; ++u) {
                    const int c = cb + u;
                    *(int4*)&Ks[sr][(c ^ (sr & 7)) * 8] = *(const int4*)(kp + c * 8);
                    *(int4*)&Vt[sr][(c ^ (sr & 7)) * 8] = *(const int4*)(vp + c * 8);
                }
            }
            __syncthreads();
            floatx4 sf[4];
            #pragma unroll
            for (int mb = 0; mb < 4; ++mb)
                #pragma unroll
                for (int e = 0; e < 4; ++e) sf[mb][e] = 0.f;
            #pragma unroll
            for (int ks = 0; ks < 2; ++ks) {
                const int krow = w * 16 + r;
                short8v kf = *(const short8v*)&Ks[krow][((ks * 4 + q) ^ (krow & 7)) * 8];
                #pragma unroll
                for (int mb = 0; mb < 4; ++mb)
                    sf[mb] = __builtin_amdgcn_mfma_f32_16x16x32_bf16(qf[mb][ks], kf, sf[mb], 0, 0, 0);
            }
            #pragma unroll
            for (int mb = 0; mb < 4; ++mb)
                #pragma unroll
                for (int i = 0; i < 4; ++i) {
                    const int rl = mb * 16 + q * 4 + i;
                    float p = (w * 16 + r > rl) ? 0.f : __expf(sf[mb][i]);
                    l_part[mb][i] += p;
                    const int c = (w * 2 + (r >> 3)) ^ (rl & 7);
                    Ps[0][rl][c * 8 + (r & 7)] = f2bf(p);
                }
            __syncthreads();
            #pragma unroll
            for (int ks = 0; ks < 2; ++ks) {
                const int prow = w * 16 + r;
                short8v pf = *(const short8v*)&Ps[0][prow][((ks * 4 + q) ^ (prow & 7)) * 8];
                #pragma unroll
                for (int nb = 0; nb < 4; ++nb) {
                    const int vrow = nb * 16 + r;
                    short8v vf = *(const short8v*)&Vt[vrow][(((ks * 4 + q) ^ (vrow & 7))) * 8];
                    o[nb] = __builtin_amdgcn_mfma_f32_16x16x32_bf16(pf, vf, o[nb], 0, 0, 0);
                }
            }
        }

        // ---- epilogue: l reduce (16 r-lanes, then cross-wave), ctx write
        #pragma unroll
        for (int mb = 0; mb < 4; ++mb)
            #pragma unroll
            for (int i = 0; i < 4; ++i) {
                float v = l_part[mb][i];
                v += __shfl_xor(v, 1, 16);
                v += __shfl_xor(v, 2, 16);
                v += __shfl_xor(v, 4, 16);
                v += __shfl_xor(v, 8, 16);
                if (r == 0) Lred[w][mb * 16 + q * 4 + i] = v;
            }
        __syncthreads();
        if (tid < 64) {
            float s = Lred[0][tid] + Lred[1][tid] + Lred[2][tid] + Lred[3][tid];
            Lr[(size_t)bh * T_LEN + t0 + tid] = s;
            Lred[0][tid] = s;
        }
        __syncthreads();
        #pragma unroll
        for (int i = 0; i < 4; ++i) {
            const int tl = w * 16 + q * 4 + i;
            const float inv = 1.0f / Lred[0][tl];
            #pragma unroll
            for (int nb = 0; nb < 4; ++nb)
                ctx[((size_t)(t0 + tl) * BSZ + b) * EMB + h * HDIM + nb * 16 + r] =
                    f2bf(o[nb][i] * inv);
        }
    }
}

// ---------------------------------------------------------------------------
// avg_w[b,t,s] = (1/H) sum_h exp(qk) / l_h[t]. 128x128 output tiles (halves
// staging traffic vs 64x64), 2 heads per staging round, Lr pre-inverted in
// LDS. Same bf16 inputs + MFMA as flash so scores match bitwise.
// ---------------------------------------------------------------------------
__global__ __launch_bounds__(256) void avg_w_k(const short* __restrict__ qk,
        const float* __restrict__ Lr, float* __restrict__ avg) {
    const int s0 = blockIdx.x * 128, t0 = blockIdx.y * 128, b = blockIdx.z;
    const int tid = threadIdx.x;
    float* outb = avg + (size_t)b * T_LEN * T_LEN;
    if (s0 > t0) {   // fully masked 128-tile: zero-fill (d_out is poisoned)
        const float4 z = make_float4(0.f, 0.f, 0.f, 0.f);
        const int row = tid >> 1;
        #pragma unroll
        for (int u = 0; u < 16; ++u)
            *(float4*)&outb[(size_t)(t0 + row) * T_LEN + s0 + ((tid & 1) * 16 + u) * 4] = z;
        return;
    }
    __shared__ short Qs[128][128];
    __shared__ short Ks[128][128];
    __shared__ float Lbuf[NHEAD][128];
    const int lane = tid & 63, w = tid >> 6;
    const int q = lane >> 4, r = lane & 15;
    const int wr = w >> 1, wc = w & 1;
    const short* qbase = qk + (size_t)b * QK_LD;
    const int RS = BSZ * QK_LD;
    const bool diag = (s0 == t0);

    // pre-inverted softmax denominators for this t-range, all heads
    #pragma unroll
    for (int u = 0; u < 8; ++u) {
        const int li = tid * 8 + u;
        const int h = li >> 7, tl = li & 127;
        Lbuf[h][tl] = 0.0625f / Lr[(size_t)(b * NHEAD + h) * T_LEN + t0 + tl];
    }

    floatx4 acc[4][4];
    #pragma unroll
    for (int mb = 0; mb < 4; ++mb)
        #pragma unroll
        for (int nb = 0; nb < 4; ++nb)
            #pragma unroll
            for (int e = 0; e < 4; ++e) acc[mb][nb][e] = 0.f;

    for (int hp = 0; hp < 8; ++hp) {       // head pairs
        const short* qh = qbase + hp * 128;
        const short* kh = qbase + EMB + hp * 128;
        __syncthreads();
        {   // 128 rows x 16 chunks each, 8 int4/thread/array
            const int sr = tid >> 1, cb = (tid & 1) * 8;
            const short* qp = qh + (size_t)(t0 + sr) * RS;
            const short* kp = kh + (size_t)(s0 + sr) * RS;
            #pragma unroll
            for (int u = 0; u < 8; ++u) {
                const int c = cb + u;
                const int pc = (c & 8) | ((c & 7) ^ (sr & 7));
                *(int4*)&Qs[sr][pc * 8] = *(const int4*)(qp + c * 8);
                *(int4*)&Ks[sr][pc * 8] = *(const int4*)(kp + c * 8);
            }
        }
        __syncthreads();

        #pragma unroll
        for (int hs = 0; hs < 2; ++hs) {
            const int h = hp * 2 + hs;
            short8v qf[4][2];
            #pragma unroll
            for (int mb = 0; mb < 4; ++mb)
                #pragma unroll
                for (int ks = 0; ks < 2; ++ks) {
                    const int row = wr * 64 + mb * 16 + r;
                    qf[mb][ks] = *(const short8v*)
                        &Qs[row][((hs * 8) | ((ks * 4 + q) ^ (row & 7))) * 8];
                }
            #pragma unroll
            for (int nb = 0; nb < 4; ++nb) {
                const int krow = wc * 64 + nb * 16 + r;
                short8v kf0 = *(const short8v*)
                    &Ks[krow][((hs * 8) | (q ^ (krow & 7))) * 8];
                short8v kf1 = *(const short8v*)
                    &Ks[krow][((hs * 8) | ((4 + q) ^ (krow & 7))) * 8];
                floatx4 sf[4];
                #pragma unroll
                for (int mb = 0; mb < 4; ++mb)
                    #pragma unroll
                    for (int e = 0; e < 4; ++e) sf[mb][e] = 0.f;
                #pragma unroll
                for (int mb = 0; mb < 4; ++mb)
                    sf[mb] = __builtin_amdgcn_mfma_f32_16x16x32_bf16(qf[mb][0], kf0, sf[mb], 0, 0, 0);
                #pragma unroll
                for (int mb = 0; mb < 4; ++mb)
                    sf[mb] = __builtin_amdgcn_mfma_f32_16x16x32_bf16(qf[mb][1], kf1, sf[mb], 0, 0, 0);
                #pragma unroll
                for (int mb = 0; mb < 4; ++mb)
                    #pragma unroll
                    for (int i = 0; i < 4; ++i) {
                        const int tl = wr * 64 + mb * 16 + q * 4 + i;
                        const int sl = wc * 64 + nb * 16 + r;
                        const float inv = Lbuf[h][tl];
                        float e = (diag && sl > tl) ? 0.f : __expf(sf[mb][i]) * inv;
                        acc[mb][nb][i] += e;
                    }
            }
        }
    }

    #pragma unroll
    for (int mb = 0; mb < 4; ++mb)
        #pragma unroll
        for (int i = 0; i < 4; ++i) {
            const int t = t0 + wr * 64 + mb * 16 + q * 4 + i;
            #pragma unroll
            for (int nb = 0; nb < 4; ++nb)
                outb[(size_t)t * T_LEN + s0 + wc * 64 + nb * 16 + r] = acc[mb][nb][i];
        }
}

// ---------------------------------------------------------------------------
// Workspace: identical to the R4-proven 40.3 MiB layout.
// ctx ALIASES qb (qb dead after gemm1; flash writes ctx strictly after).
// ---------------------------------------------------------------------------
extern "C" void kernel_launch(void* const* d_in, const int* in_sizes, int n_in,
                              void* d_out, int out_size, void* d_ws, size_t ws_size,
                              hipStream_t stream) {
    (void)in_sizes; (void)n_in; (void)out_size; (void)ws_size;
    const float* query = (const float*)d_in[0];
    const float* w_in  = (const float*)d_in[1];
    const float* b_in  = (const float*)d_in[2];
    const float* w_out = (const float*)d_in[3];
    const float* b_out = (const float*)d_in[4];

    float* out = (float*)d_out;                           // [T,B,E] fp32
    float* avg = out + (size_t)T_LEN * BSZ * EMB;         // [B,T,T] fp32

    short* ws     = (short*)d_ws;
    short* qb     = ws;                                   // query bf16 [4096,1024]  8 MB
    short* wb_in  = qb     + (size_t)4096 * 1024;         // w_in bf16  [3072,1024]  6 MB
    short* wb_out = wb_in  + (size_t)3072 * 1024;         // w_out bf16 [1024,1024]  2 MB
    short* qkb    = wb_out + (size_t)1024 * 1024;         // q,k bf16   [4096,2048] 16 MB
    short* vTb    = qkb    + (size_t)4096 * 2048;         // V^T bf16   [B*E, T]     8 MB
    float* Lr     = (float*)(vTb + (size_t)BSZ * EMB * T_LEN);  // [B*H, T]       256 KB
    short* ctxb   = qb;                                   // ctx bf16 [4096,1024] (alias)

    f32_to_bf16_k<<<4096, 256, 0, stream>>>(query, qb,     4096 * 1024);
    f32_to_bf16_k<<<3072, 256, 0, stream>>>(w_in,  wb_in,  3072 * 1024);
    f32_to_bf16_k<<<1024, 256, 0, stream>>>(w_out, wb_out, 1024 * 1024);

    // QKV projection: q,k -> qkb (q scaled by 1/8), v -> vTb (transposed)
    gemm_bf16<<<dim3(24, 32), 256, 0, stream>>>(qb, wb_in, b_in, qkb, vTb,
                                                4096, 3072, 1024, EMB, 1, QK_LD);
    flash_fwd<<<dim3(16, 32), 256, 0, stream>>>(qkb, vTb, ctxb, Lr);
    avg_w_k<<<dim3(16, 16, 2), 256, 0, stream>>>(qkb, Lr, avg);
    gemm_bf16<<<dim3(8, 32), 256, 0, stream>>>(ctxb, wb_out, b_out, out, (short*)0,
                                               4096, 1024, 1024, 0, 0, 1024);
}

// Round 7
// 260.758 us; speedup vs baseline: 1.3628x; 1.3628x over previous
//
#include <hip/hip_runtime.h>
#include <math.h>

#define T_LEN 2048
#define BSZ 2
#define EMB 1024
#define NHEAD 16
#define HDIM 64
#define QK_LD 2048   // q,k packed [T*B, 2E]

typedef __attribute__((ext_vector_type(8))) short short8v;   // 8 bf16 (4 VGPRs)
typedef __attribute__((ext_vector_type(4))) float floatx4;   // MFMA C/D

__device__ __forceinline__ short f2bf(float f) {
    unsigned u = __float_as_uint(f);
    u += 0x7fffu + ((u >> 16) & 1u);   // RNE
    return (short)(u >> 16);
}

// ---------------------------------------------------------------------------
__global__ __launch_bounds__(256) void f32_to_bf16_k(const float* __restrict__ src,
                                                     short* __restrict__ dst, int n) {
    int i = (blockIdx.x * 256 + threadIdx.x) * 4;
    if (i >= n) return;
    float4 v = *(const float4*)(src + i);
    short4 o = make_short4(f2bf(v.x), f2bf(v.y), f2bf(v.z), f2bf(v.w));
    *(short4*)(dst + i) = o;
}

// ---------------------------------------------------------------------------
// C = A[M,K]*B[N,K]^T + bias; cols < scale_cols get *0.125 (q scale).
// If vTout != 0, cols >= 2*EMB are written TRANSPOSED to vT[b][e][t] (bf16).
// bf16 MFMA 16x16x32, 128x128 tile, BK=32, 4 waves (2x2), 4x4 frags/wave.
// ---------------------------------------------------------------------------
__global__ __launch_bounds__(256) void gemm_bf16(const short* __restrict__ A,
        const short* __restrict__ B, const float* __restrict__ bias,
        void* __restrict__ Cout, short* __restrict__ vTout,
        int M, int N, int K, int scale_cols, int out_bf16, int ldC) {
    __shared__ short As[128][32];
    __shared__ short Bs[128][32];
    const int tid = threadIdx.x;
    const int m0 = blockIdx.y * 128, n0 = blockIdx.x * 128;
    const int lane = tid & 63, w = tid >> 6;
    const int q = lane >> 4, r = lane & 15;
    const int wr = w >> 1, wc = w & 1;
    const int srow = tid >> 2, sc4 = tid & 3;
    const int sp = (sc4 ^ ((srow >> 1) & 3)) * 8;

    const short* Arow0 = A + (size_t)(m0 + srow) * K + sc4 * 8;
    const short* Arow1 = Arow0 + (size_t)64 * K;
    const short* Brow0 = B + (size_t)(n0 + srow) * K + sc4 * 8;
    const short* Brow1 = Brow0 + (size_t)64 * K;

    floatx4 acc[4][4];
    #pragma unroll
    for (int a = 0; a < 4; ++a)
        #pragma unroll
        for (int b2 = 0; b2 < 4; ++b2)
            #pragma unroll
            for (int e = 0; e < 4; ++e) acc[a][b2][e] = 0.f;

    for (int k0 = 0; k0 < K; k0 += 32) {
        int4 a0 = *(const int4*)(Arow0 + k0);
        int4 a1 = *(const int4*)(Arow1 + k0);
        int4 b0 = *(const int4*)(Brow0 + k0);
        int4 b1 = *(const int4*)(Brow1 + k0);
        __syncthreads();
        *(int4*)&As[srow][sp] = a0;
        *(int4*)&As[64 + srow][sp] = a1;
        *(int4*)&Bs[srow][sp] = b0;
        *(int4*)&Bs[64 + srow][sp] = b1;
        __syncthreads();
        short8v af[4], bfr[4];
        #pragma unroll
        for (int mb = 0; mb < 4; ++mb) {
            int row = wr * 64 + mb * 16 + r;
            af[mb] = *(const short8v*)&As[row][(q ^ ((row >> 1) & 3)) * 8];
        }
        #pragma unroll
        for (int nb = 0; nb < 4; ++nb) {
            int row = wc * 64 + nb * 16 + r;
            bfr[nb] = *(const short8v*)&Bs[row][(q ^ ((row >> 1) & 3)) * 8];
        }
        #pragma unroll
        for (int mb = 0; mb < 4; ++mb)
            #pragma unroll
            for (int nb = 0; nb < 4; ++nb)
                acc[mb][nb] = __builtin_amdgcn_mfma_f32_16x16x32_bf16(af[mb], bfr[nb], acc[mb][nb], 0, 0, 0);
    }

    #pragma unroll
    for (int nb = 0; nb < 4; ++nb) {
        const int col = n0 + wc * 64 + nb * 16 + r;
        const float bi = bias[col];
        const float sc = (col < scale_cols) ? 0.125f : 1.0f;
        if (vTout && col >= 2 * EMB) {
            const int e = col - 2 * EMB;
            #pragma unroll
            for (int mb = 0; mb < 4; ++mb) {
                const int base = m0 + wr * 64 + mb * 16 + q * 4;   // multiple of 4
                float v0 = acc[mb][nb][0] + bi, v1 = acc[mb][nb][1] + bi;
                float v2 = acc[mb][nb][2] + bi, v3 = acc[mb][nb][3] + bi;
                // rows (t*2+b): i=0,2 -> b=0 t,t+1 ; i=1,3 -> b=1 t,t+1
                unsigned lo = (unsigned short)f2bf(v0) | ((unsigned)(unsigned short)f2bf(v2) << 16);
                unsigned hi = (unsigned short)f2bf(v1) | ((unsigned)(unsigned short)f2bf(v3) << 16);
                *(unsigned*)&vTout[(size_t)e * T_LEN + (base >> 1)]         = lo;
                *(unsigned*)&vTout[((size_t)EMB + e) * T_LEN + (base >> 1)] = hi;
            }
        } else {
            #pragma unroll
            for (int mb = 0; mb < 4; ++mb)
                #pragma unroll
                for (int i = 0; i < 4; ++i) {
                    const int rowg = m0 + wr * 64 + mb * 16 + q * 4 + i;
                    const float v = (acc[mb][nb][i] + bi) * sc;
                    if (out_bf16) ((short*)Cout)[(size_t)rowg * ldC + col] = f2bf(v);
                    else          ((float*)Cout)[(size_t)rowg * ldC + col] = v;
                }
        }
    }
}

// ---------------------------------------------------------------------------
// Flash causal attention. Triangle load balance WITHOUT atomics: block
// (pairi, bh) processes ttile=pairi then ttile=31-pairi -> every block does
// exactly 33 s-tiles. 512 uniform blocks. K-loop processes 2 s-tiles per
// staging round, P double-buffered. No online max (scores provably small).
// ---------------------------------------------------------------------------
__global__ __launch_bounds__(256) void flash_fwd(const short* __restrict__ qk,
        const short* __restrict__ vT, short* __restrict__ ctx,
        float* __restrict__ Lr) {
    __shared__ short Ks[128][64];       // 2 s-tiles of K
    __shared__ short Vt[64][128];       // V^T: [d][2 s-tiles]
    __shared__ short Ps[2][64][64];     // P dbuf; Ps[0] doubles as Q staging
    __shared__ float Lred[4][64];
    const int tid = threadIdx.x;
    const int pairi = blockIdx.x;       // 0..15
    const int bh = blockIdx.y, b = bh >> 4, h = bh & 15;
    const int lane = tid & 63, w = tid >> 6;
    const int q = lane >> 4, r = lane & 15;
    const int RS = BSZ * QK_LD;

    const short* qbase = qk + (size_t)b * QK_LD + h * HDIM;
    const short* kbase = qbase + EMB;
    const short* vbase = vT + ((size_t)b * EMB + h * HDIM) * T_LEN;

    for (int pass = 0; pass < 2; ++pass) {
        const int tt = pass ? (31 - pairi) : pairi;
        const int t0 = tt << 6;
        __syncthreads();   // prior pass's Ps/Lred reads done
        {   // stage Q into Ps[0]
            const int sr = tid >> 3, c8 = tid & 7;
            *(int4*)&Ps[0][sr][(c8 ^ (sr & 7)) * 8] =
                *(const int4*)(qbase + (size_t)(t0 + sr) * RS + c8 * 8);
            *(int4*)&Ps[0][sr + 32][(c8 ^ ((sr + 32) & 7)) * 8] =
                *(const int4*)(qbase + (size_t)(t0 + sr + 32) * RS + c8 * 8);
        }
        __syncthreads();
        short8v qf[4][2];
        #pragma unroll
        for (int mb = 0; mb < 4; ++mb)
            #pragma unroll
            for (int ks = 0; ks < 2; ++ks) {
                int row = mb * 16 + r;
                qf[mb][ks] = *(const short8v*)&Ps[0][row][((ks * 4 + q) ^ (row & 7)) * 8];
            }

        float l_part[4][4];
        floatx4 o[4];
        #pragma unroll
        for (int mb = 0; mb < 4; ++mb)
            #pragma unroll
            for (int i = 0; i < 4; ++i) l_part[mb][i] = 0.f;
        #pragma unroll
        for (int nb = 0; nb < 4; ++nb)
            #pragma unroll
            for (int e = 0; e < 4; ++e) o[nb][e] = 0.f;

        const int ntiles = tt + 1;
        int s2 = 0;
        for (; s2 + 2 <= ntiles; s2 += 2) {   // paired rounds: 128 s per stage
            __syncthreads();
            {   // K: 128 rows x 8 chunks (4 int4/thread)
                const int sr = tid >> 1, cb = (tid & 1) * 4;
                const short* kp = kbase + (size_t)(s2 * 64 + sr) * RS;
                #pragma unroll
                for (int u = 0; u < 4; ++u) {
                    const int c = cb + u;
                    *(int4*)&Ks[sr][(c ^ (sr & 7)) * 8] = *(const int4*)(kp + c * 8);
                }
                // V^T: 64 rows x 16 chunks (4 int4/thread)
                const int vr = tid >> 2, vb0 = (tid & 3) * 4;
                const short* vp = vbase + (size_t)vr * T_LEN + s2 * 64;
                #pragma unroll
                for (int u = 0; u < 4; ++u) {
                    const int c = vb0 + u;
                    const int pc = (c & 8) | ((c & 7) ^ (vr & 7));
                    *(int4*)&Vt[vr][pc * 8] = *(const int4*)(vp + c * 8);
                }
            }
            __syncthreads();
            #pragma unroll
            for (int t2 = 0; t2 < 2; ++t2) {   // QK + P for both tiles
                floatx4 sf[4];
                #pragma unroll
                for (int mb = 0; mb < 4; ++mb)
                    #pragma unroll
                    for (int e = 0; e < 4; ++e) sf[mb][e] = 0.f;
                #pragma unroll
                for (int ks = 0; ks < 2; ++ks) {
                    const int krow = t2 * 64 + w * 16 + r;
                    short8v kf = *(const short8v*)&Ks[krow][((ks * 4 + q) ^ (krow & 7)) * 8];
                    #pragma unroll
                    for (int mb = 0; mb < 4; ++mb)
                        sf[mb] = __builtin_amdgcn_mfma_f32_16x16x32_bf16(qf[mb][ks], kf, sf[mb], 0, 0, 0);
                }
                const bool diag = (s2 + t2 == tt);
                #pragma unroll
                for (int mb = 0; mb < 4; ++mb)
                    #pragma unroll
                    for (int i = 0; i < 4; ++i) {
                        const int rl = mb * 16 + q * 4 + i;
                        float p = (diag && (w * 16 + r > rl)) ? 0.f : __expf(sf[mb][i]);
                        l_part[mb][i] += p;
                        const int c = (w * 2 + (r >> 3)) ^ (rl & 7);
                        Ps[t2][rl][c * 8 + (r & 7)] = f2bf(p);
                    }
            }
            __syncthreads();
            #pragma unroll
            for (int ks = 0; ks < 2; ++ks) {   // PV both s-halves
                const int prow = w * 16 + r;
                const int pcp = ((ks * 4 + q) ^ (prow & 7)) * 8;
                short8v pfA = *(const short8v*)&Ps[0][prow][pcp];
                short8v pfB = *(const short8v*)&Ps[1][prow][pcp];
                #pragma unroll
                for (int nb = 0; nb < 4; ++nb) {
                    const int vrow = nb * 16 + r;
                    const int pcv = (ks * 4 + q) ^ (vrow & 7);
                    short8v vfA = *(const short8v*)&Vt[vrow][pcv * 8];
                    short8v vfB = *(const short8v*)&Vt[vrow][(8 | pcv) * 8];
                    o[nb] = __builtin_amdgcn_mfma_f32_16x16x32_bf16(pfA, vfA, o[nb], 0, 0, 0);
                    o[nb] = __builtin_amdgcn_mfma_f32_16x16x32_bf16(pfB, vfB, o[nb], 0, 0, 0);
                }
            }
        }
        if (s2 < ntiles) {   // odd tail: single tile s2 == tt (diagonal)
            __syncthreads();
            {   // 64 rows x 8 chunks each (2 int4/thread)
                const int sr = tid >> 2, cb = (tid & 3) * 2;
                const short* kp = kbase + (size_t)(s2 * 64 + sr) * RS;
                const short* vp = vbase + (size_t)sr * T_LEN + s2 * 64;
                #pragma unroll
                for (int u = 0; u < 2; ++u) {
                    const int c = cb + u;
                    *(int4*)&Ks[sr][(c ^ (sr & 7)) * 8] = *(const int4*)(kp + c * 8);
                    *(int4*)&Vt[sr][(c ^ (sr & 7)) * 8] = *(const int4*)(vp + c * 8);
                }
            }
            __syncthreads();
            floatx4 sf[4];
            #pragma unroll
            for (int mb = 0; mb < 4; ++mb)
                #pragma unroll
                for (int e = 0; e < 4; ++e) sf[mb][e] = 0.f;
            #pragma unroll
            for (int ks = 0; ks < 2; ++ks) {
                const int krow = w * 16 + r;
                short8v kf = *(const short8v*)&Ks[krow][((ks * 4 + q) ^ (krow & 7)) * 8];
                #pragma unroll
                for (int mb = 0; mb < 4; ++mb)
                    sf[mb] = __builtin_amdgcn_mfma_f32_16x16x32_bf16(qf[mb][ks], kf, sf[mb], 0, 0, 0);
            }
            #pragma unroll
            for (int mb = 0; mb < 4; ++mb)
                #pragma unroll
                for (int i = 0; i < 4; ++i) {
                    const int rl = mb * 16 + q * 4 + i;
                    float p = (w * 16 + r > rl) ? 0.f : __expf(sf[mb][i]);
                    l_part[mb][i] += p;
                    const int c = (w * 2 + (r >> 3)) ^ (rl & 7);
                    Ps[0][rl][c * 8 + (r & 7)] = f2bf(p);
                }
            __syncthreads();
            #pragma unroll
            for (int ks = 0; ks < 2; ++ks) {
                const int prow = w * 16 + r;
                short8v pf = *(const short8v*)&Ps[0][prow][((ks * 4 + q) ^ (prow & 7)) * 8];
                #pragma unroll
                for (int nb = 0; nb < 4; ++nb) {
                    const int vrow = nb * 16 + r;
                    short8v vf = *(const short8v*)&Vt[vrow][(((ks * 4 + q) ^ (vrow & 7))) * 8];
                    o[nb] = __builtin_amdgcn_mfma_f32_16x16x32_bf16(pf, vf, o[nb], 0, 0, 0);
                }
            }
        }

        // ---- epilogue: l reduce (16 r-lanes, then cross-wave), ctx write
        #pragma unroll
        for (int mb = 0; mb < 4; ++mb)
            #pragma unroll
            for (int i = 0; i < 4; ++i) {
                float v = l_part[mb][i];
                v += __shfl_xor(v, 1, 16);
                v += __shfl_xor(v, 2, 16);
                v += __shfl_xor(v, 4, 16);
                v += __shfl_xor(v, 8, 16);
                if (r == 0) Lred[w][mb * 16 + q * 4 + i] = v;
            }
        __syncthreads();
        if (tid < 64) {
            float s = Lred[0][tid] + Lred[1][tid] + Lred[2][tid] + Lred[3][tid];
            Lr[(size_t)bh * T_LEN + t0 + tid] = s;
            Lred[0][tid] = s;
        }
        __syncthreads();
        #pragma unroll
        for (int i = 0; i < 4; ++i) {
            const int tl = w * 16 + q * 4 + i;
            const float inv = 1.0f / Lred[0][tl];
            #pragma unroll
            for (int nb = 0; nb < 4; ++nb)
                ctx[((size_t)(t0 + tl) * BSZ + b) * EMB + h * HDIM + nb * 16 + r] =
                    f2bf(o[nb][i] * inv);
        }
    }
}

// ---------------------------------------------------------------------------
// avg_w[b,t,s] = (1/H) sum_h exp(qk) / l_h[t]. 64x64 output tiles (1056
// working blocks -> ~4/CU), 2 heads per staging round (32 KB LDS -> 5
// blocks/CU), denominators pre-inverted once into Lbuf (mul per element
// instead of a divide). Same bf16 inputs + MFMA as flash (errors cancel).
// ---------------------------------------------------------------------------
__global__ __launch_bounds__(256) void avg_w_k(const short* __restrict__ qk,
        const float* __restrict__ Lr, float* __restrict__ avg) {
    const int s0 = blockIdx.x * 64, t0 = blockIdx.y * 64, b = blockIdx.z;
    const int tid = threadIdx.x;
    float* outb = avg + (size_t)b * T_LEN * T_LEN;
    if (s0 > t0) {   // fully masked tile: zero-fill (d_out is poisoned)
        const int ty = tid >> 4, tx = tid & 15;
        const float4 z = make_float4(0.f, 0.f, 0.f, 0.f);
        #pragma unroll
        for (int i = 0; i < 4; ++i)
            *(float4*)&outb[(size_t)(t0 + ty * 4 + i) * T_LEN + s0 + tx * 4] = z;
        return;
    }
    __shared__ short Qs[64][128];
    __shared__ short Ks[64][128];
    __shared__ float Lbuf[NHEAD][64];
    const int lane = tid & 63, w = tid >> 6;
    const int q = lane >> 4, r = lane & 15;
    const int srow = tid >> 2, c4 = (tid & 3) * 4;   // 4 chunks of 16B per thread
    const short* qbase = qk + (size_t)b * QK_LD;
    const int RS = BSZ * QK_LD;

    // pre-inverted denominators: 16 heads x 64 t-rows (published by 1st barrier)
    #pragma unroll
    for (int u = 0; u < 4; ++u) {
        const int li = tid * 4 + u;
        const int h = li >> 6, tl = li & 63;
        Lbuf[h][tl] = 0.0625f / Lr[(size_t)(b * NHEAD + h) * T_LEN + t0 + tl];
    }

    floatx4 acc[4];
    #pragma unroll
    for (int nb = 0; nb < 4; ++nb)
        #pragma unroll
        for (int e = 0; e < 4; ++e) acc[nb][e] = 0.f;

    for (int hp = 0; hp < 8; ++hp) {       // head pairs
        const short* qh = qbase + hp * 128;
        const short* kh = qbase + EMB + hp * 128;
        __syncthreads();
        #pragma unroll
        for (int u = 0; u < 4; ++u) {
            const int c = c4 + u;                              // chunk 0..15
            const int pc = (c & 8) | ((c & 7) ^ (srow & 7));   // swizzle within head
            *(int4*)&Qs[srow][pc * 8] =
                *(const int4*)(qh + (size_t)(t0 + srow) * RS + c * 8);
            *(int4*)&Ks[srow][pc * 8] =
                *(const int4*)(kh + (size_t)(s0 + srow) * RS + c * 8);
        }
        __syncthreads();

        #pragma unroll
        for (int hs = 0; hs < 2; ++hs) {
            const int h = hp * 2 + hs;
            floatx4 sf[4];
            #pragma unroll
            for (int nb = 0; nb < 4; ++nb)
                #pragma unroll
                for (int e = 0; e < 4; ++e) sf[nb][e] = 0.f;
            #pragma unroll
            for (int ks = 0; ks < 2; ++ks) {
                const int qrow = w * 16 + r;
                short8v qfr = *(const short8v*)
                    &Qs[qrow][((hs * 8) | ((ks * 4 + q) ^ (qrow & 7))) * 8];
                #pragma unroll
                for (int nb = 0; nb < 4; ++nb) {
                    const int krow = nb * 16 + r;
                    short8v kfr = *(const short8v*)
                        &Ks[krow][((hs * 8) | ((ks * 4 + q) ^ (krow & 7))) * 8];
                    sf[nb] = __builtin_amdgcn_mfma_f32_16x16x32_bf16(qfr, kfr, sf[nb], 0, 0, 0);
                }
            }
            #pragma unroll
            for (int i = 0; i < 4; ++i) {
                const int tl = w * 16 + q * 4 + i;
                const float inv = Lbuf[h][tl];
                #pragma unroll
                for (int nb = 0; nb < 4; ++nb) {
                    float e = (s0 == t0 && (nb * 16 + r > tl))
                              ? 0.f : __expf(sf[nb][i]) * inv;
                    acc[nb][i] += e;
                }
            }
        }
    }

    #pragma unroll
    for (int i = 0; i < 4; ++i) {
        const int t = t0 + w * 16 + q * 4 + i;
        #pragma unroll
        for (int nb = 0; nb < 4; ++nb)
            outb[(size_t)t * T_LEN + s0 + nb * 16 + r] = acc[nb][i];
    }
}

// ---------------------------------------------------------------------------
// Workspace: identical to the R4-proven 40.3 MiB layout.
// ctx ALIASES qb (qb dead after gemm1; flash writes ctx strictly after).
// ---------------------------------------------------------------------------
extern "C" void kernel_launch(void* const* d_in, const int* in_sizes, int n_in,
                              void* d_out, int out_size, void* d_ws, size_t ws_size,
                              hipStream_t stream) {
    (void)in_sizes; (void)n_in; (void)out_size; (void)ws_size;
    const float* query = (const float*)d_in[0];
    const float* w_in  = (const float*)d_in[1];
    const float* b_in  = (const float*)d_in[2];
    const float* w_out = (const float*)d_in[3];
    const float* b_out = (const float*)d_in[4];

    float* out = (float*)d_out;                           // [T,B,E] fp32
    float* avg = out + (size_t)T_LEN * BSZ * EMB;         // [B,T,T] fp32

    short* ws     = (short*)d_ws;
    short* qb     = ws;                                   // query bf16 [4096,1024]  8 MB
    short* wb_in  = qb     + (size_t)4096 * 1024;         // w_in bf16  [3072,1024]  6 MB
    short* wb_out = wb_in  + (size_t)3072 * 1024;         // w_out bf16 [1024,1024]  2 MB
    short* qkb    = wb_out + (size_t)1024 * 1024;         // q,k bf16   [4096,2048] 16 MB
    short* vTb    = qkb    + (size_t)4096 * 2048;         // V^T bf16   [B*E, T]     8 MB
    float* Lr     = (float*)(vTb + (size_t)BSZ * EMB * T_LEN);  // [B*H, T]       256 KB
    short* ctxb   = qb;                                   // ctx bf16 [4096,1024] (alias)

    f32_to_bf16_k<<<4096, 256, 0, stream>>>(query, qb,     4096 * 1024);
    f32_to_bf16_k<<<3072, 256, 0, stream>>>(w_in,  wb_in,  3072 * 1024);
    f32_to_bf16_k<<<1024, 256, 0, stream>>>(w_out, wb_out, 1024 * 1024);

    // QKV projection: q,k -> qkb (q scaled by 1/8), v -> vTb (transposed)
    gemm_bf16<<<dim3(24, 32), 256, 0, stream>>>(qb, wb_in, b_in, qkb, vTb,
                                                4096, 3072, 1024, EMB, 1, QK_LD);
    flash_fwd<<<dim3(16, 32), 256, 0, stream>>>(qkb, vTb, ctxb, Lr);
    avg_w_k<<<dim3(32, 32, 2), 256, 0, stream>>>(qkb, Lr, avg);
    gemm_bf16<<<dim3(8, 32), 256, 0, stream>>>(ctxb, wb_out, b_out, out, (short*)0,
                                               4096, 1024, 1024, 0, 0, 1024);
}

// Round 8
// 259.738 us; speedup vs baseline: 1.3682x; 1.0039x over previous
//
#include <hip/hip_runtime.h>
#include <math.h>

#define T_LEN 2048
#define BSZ 2
#define EMB 1024
#define NHEAD 16
#define HDIM 64
#define QK_LD 2048   // q,k packed [T*B, 2E]

typedef __attribute__((ext_vector_type(8))) short short8v;   // 8 bf16 (4 VGPRs)
typedef __attribute__((ext_vector_type(4))) float floatx4;   // MFMA C/D

__device__ __forceinline__ short f2bf(float f) {
    unsigned u = __float_as_uint(f);
    u += 0x7fffu + ((u >> 16) & 1u);   // RNE
    return (short)(u >> 16);
}

// ---------------------------------------------------------------------------
__global__ __launch_bounds__(256) void f32_to_bf16_k(const float* __restrict__ src,
                                                     short* __restrict__ dst, int n) {
    int i = (blockIdx.x * 256 + threadIdx.x) * 4;
    if (i >= n) return;
    float4 v = *(const float4*)(src + i);
    short4 o = make_short4(f2bf(v.x), f2bf(v.y), f2bf(v.z), f2bf(v.w));
    *(short4*)(dst + i) = o;
}

// ---------------------------------------------------------------------------
// C = A[M,K]*B[N,K]^T + bias; cols < scale_cols get *0.125 (q scale).
// a_fp32: A is fp32, converted to bf16 during LDS staging (saves a separate
// convert pass: 16.8 MB direct vs 33.6 MB convert+reread).
// If vTout != 0, cols >= 2*EMB are written TRANSPOSED to vT[b][e][t] (bf16).
// bf16 MFMA 16x16x32, 128x128 tile, BK=32, 4 waves (2x2), 4x4 frags/wave.
// ---------------------------------------------------------------------------
__global__ __launch_bounds__(256) void gemm_bf16(const void* __restrict__ Ain,
        const short* __restrict__ B, const float* __restrict__ bias,
        void* __restrict__ Cout, short* __restrict__ vTout,
        int M, int N, int K, int scale_cols, int out_bf16, int ldC, int a_fp32) {
    __shared__ short As[128][32];
    __shared__ short Bs[128][32];
    const int tid = threadIdx.x;
    const int m0 = blockIdx.y * 128, n0 = blockIdx.x * 128;
    const int lane = tid & 63, w = tid >> 6;
    const int q = lane >> 4, r = lane & 15;
    const int wr = w >> 1, wc = w & 1;
    const int srow = tid >> 2, sc4 = tid & 3;
    const int sp = (sc4 ^ ((srow >> 1) & 3)) * 8;

    const short* Brow0 = B + (size_t)(n0 + srow) * K + sc4 * 8;
    const short* Brow1 = Brow0 + (size_t)64 * K;

    floatx4 acc[4][4];
    #pragma unroll
    for (int a = 0; a < 4; ++a)
        #pragma unroll
        for (int b2 = 0; b2 < 4; ++b2)
            #pragma unroll
            for (int e = 0; e < 4; ++e) acc[a][b2][e] = 0.f;

    for (int k0 = 0; k0 < K; k0 += 32) {
        int4 a0, a1;
        if (a_fp32) {
            const float* Af = (const float*)Ain;
            const float* p0 = Af + (size_t)(m0 + srow) * K + sc4 * 8 + k0;
            const float* p1 = p0 + (size_t)64 * K;
            float4 f00 = *(const float4*)p0, f01 = *(const float4*)(p0 + 4);
            float4 f10 = *(const float4*)p1, f11 = *(const float4*)(p1 + 4);
            short4 s00 = make_short4(f2bf(f00.x), f2bf(f00.y), f2bf(f00.z), f2bf(f00.w));
            short4 s01 = make_short4(f2bf(f01.x), f2bf(f01.y), f2bf(f01.z), f2bf(f01.w));
            short4 s10 = make_short4(f2bf(f10.x), f2bf(f10.y), f2bf(f10.z), f2bf(f10.w));
            short4 s11 = make_short4(f2bf(f11.x), f2bf(f11.y), f2bf(f11.z), f2bf(f11.w));
            a0 = make_int4(*(int*)&s00.x, *(int*)&s00.z, *(int*)&s01.x, *(int*)&s01.z);
            a1 = make_int4(*(int*)&s10.x, *(int*)&s10.z, *(int*)&s11.x, *(int*)&s11.z);
        } else {
            const short* As8 = (const short*)Ain + (size_t)(m0 + srow) * K + sc4 * 8 + k0;
            a0 = *(const int4*)As8;
            a1 = *(const int4*)(As8 + (size_t)64 * K);
        }
        int4 b0 = *(const int4*)(Brow0 + k0);
        int4 b1 = *(const int4*)(Brow1 + k0);
        __syncthreads();
        *(int4*)&As[srow][sp] = a0;
        *(int4*)&As[64 + srow][sp] = a1;
        *(int4*)&Bs[srow][sp] = b0;
        *(int4*)&Bs[64 + srow][sp] = b1;
        __syncthreads();
        short8v af[4], bfr[4];
        #pragma unroll
        for (int mb = 0; mb < 4; ++mb) {
            int row = wr * 64 + mb * 16 + r;
            af[mb] = *(const short8v*)&As[row][(q ^ ((row >> 1) & 3)) * 8];
        }
        #pragma unroll
        for (int nb = 0; nb < 4; ++nb) {
            int row = wc * 64 + nb * 16 + r;
            bfr[nb] = *(const short8v*)&Bs[row][(q ^ ((row >> 1) & 3)) * 8];
        }
        #pragma unroll
        for (int mb = 0; mb < 4; ++mb)
            #pragma unroll
            for (int nb = 0; nb < 4; ++nb)
                acc[mb][nb] = __builtin_amdgcn_mfma_f32_16x16x32_bf16(af[mb], bfr[nb], acc[mb][nb], 0, 0, 0);
    }

    #pragma unroll
    for (int nb = 0; nb < 4; ++nb) {
        const int col = n0 + wc * 64 + nb * 16 + r;
        const float bi = bias[col];
        const float sc = (col < scale_cols) ? 0.125f : 1.0f;
        if (vTout && col >= 2 * EMB) {
            const int e = col - 2 * EMB;
            #pragma unroll
            for (int mb = 0; mb < 4; ++mb) {
                const int base = m0 + wr * 64 + mb * 16 + q * 4;   // multiple of 4
                float v0 = acc[mb][nb][0] + bi, v1 = acc[mb][nb][1] + bi;
                float v2 = acc[mb][nb][2] + bi, v3 = acc[mb][nb][3] + bi;
                // rows (t*2+b): i=0,2 -> b=0 t,t+1 ; i=1,3 -> b=1 t,t+1
                unsigned lo = (unsigned short)f2bf(v0) | ((unsigned)(unsigned short)f2bf(v2) << 16);
                unsigned hi = (unsigned short)f2bf(v1) | ((unsigned)(unsigned short)f2bf(v3) << 16);
                *(unsigned*)&vTout[(size_t)e * T_LEN + (base >> 1)]         = lo;
                *(unsigned*)&vTout[((size_t)EMB + e) * T_LEN + (base >> 1)] = hi;
            }
        } else {
            #pragma unroll
            for (int mb = 0; mb < 4; ++mb)
                #pragma unroll
                for (int i = 0; i < 4; ++i) {
                    const int rowg = m0 + wr * 64 + mb * 16 + q * 4 + i;
                    const float v = (acc[mb][nb][i] + bi) * sc;
                    if (out_bf16) ((short*)Cout)[(size_t)rowg * ldC + col] = f2bf(v);
                    else          ((float*)Cout)[(size_t)rowg * ldC + col] = v;
                }
        }
    }
}

// ---------------------------------------------------------------------------
// Flash causal attention. Triangle pairing (ttile=pairi then 31-pairi, 33
// s-tiles per block, no atomics). GRID IS (bh, pairi): linear%8 = bh%8 so
// each XCD hosts only 4 bh values -> K/V working set 2 MB fits per-XCD L2
// (R7 counter: 125 MB FETCH = 5x overfetch from all-32-bh-per-XCD thrash).
// 2 s-tiles per staging round, P double-buffered, no online max.
// ---------------------------------------------------------------------------
__global__ __launch_bounds__(256) void flash_fwd(const short* __restrict__ qk,
        const short* __restrict__ vT, short* __restrict__ ctx,
        float* __restrict__ Lr) {
    __shared__ short Ks[128][64];       // 2 s-tiles of K
    __shared__ short Vt[64][128];       // V^T: [d][2 s-tiles]
    __shared__ short Ps[2][64][64];     // P dbuf; Ps[0] doubles as Q staging
    __shared__ float Lred[4][64];
    const int tid = threadIdx.x;
    const int bh = blockIdx.x;          // XCD locality: linear%8 = bh%8
    const int pairi = blockIdx.y;       // 0..15
    const int b = bh >> 4, h = bh & 15;
    const int lane = tid & 63, w = tid >> 6;
    const int q = lane >> 4, r = lane & 15;
    const int RS = BSZ * QK_LD;

    const short* qbase = qk + (size_t)b * QK_LD + h * HDIM;
    const short* kbase = qbase + EMB;
    const short* vbase = vT + ((size_t)b * EMB + h * HDIM) * T_LEN;

    for (int pass = 0; pass < 2; ++pass) {
        const int tt = pass ? (31 - pairi) : pairi;
        const int t0 = tt << 6;
        __syncthreads();   // prior pass's Ps/Lred reads done
        {   // stage Q into Ps[0]
            const int sr = tid >> 3, c8 = tid & 7;
            *(int4*)&Ps[0][sr][(c8 ^ (sr & 7)) * 8] =
                *(const int4*)(qbase + (size_t)(t0 + sr) * RS + c8 * 8);
            *(int4*)&Ps[0][sr + 32][(c8 ^ ((sr + 32) & 7)) * 8] =
                *(const int4*)(qbase + (size_t)(t0 + sr + 32) * RS + c8 * 8);
        }
        __syncthreads();
        short8v qf[4][2];
        #pragma unroll
        for (int mb = 0; mb < 4; ++mb)
            #pragma unroll
            for (int ks = 0; ks < 2; ++ks) {
                int row = mb * 16 + r;
                qf[mb][ks] = *(const short8v*)&Ps[0][row][((ks * 4 + q) ^ (row & 7)) * 8];
            }

        float l_part[4][4];
        floatx4 o[4];
        #pragma unroll
        for (int mb = 0; mb < 4; ++mb)
            #pragma unroll
            for (int i = 0; i < 4; ++i) l_part[mb][i] = 0.f;
        #pragma unroll
        for (int nb = 0; nb < 4; ++nb)
            #pragma unroll
            for (int e = 0; e < 4; ++e) o[nb][e] = 0.f;

        const int ntiles = tt + 1;
        int s2 = 0;
        for (; s2 + 2 <= ntiles; s2 += 2) {   // paired rounds: 128 s per stage
            __syncthreads();
            {   // K: 128 rows x 8 chunks (4 int4/thread)
                const int sr = tid >> 1, cb = (tid & 1) * 4;
                const short* kp = kbase + (size_t)(s2 * 64 + sr) * RS;
                #pragma unroll
                for (int u = 0; u < 4; ++u) {
                    const int c = cb + u;
                    *(int4*)&Ks[sr][(c ^ (sr & 7)) * 8] = *(const int4*)(kp + c * 8);
                }
                // V^T: 64 rows x 16 chunks (4 int4/thread)
                const int vr = tid >> 2, vb0 = (tid & 3) * 4;
                const short* vp = vbase + (size_t)vr * T_LEN + s2 * 64;
                #pragma unroll
                for (int u = 0; u < 4; ++u) {
                    const int c = vb0 + u;
                    const int pc = (c & 8) | ((c & 7) ^ (vr & 7));
                    *(int4*)&Vt[vr][pc * 8] = *(const int4*)(vp + c * 8);
                }
            }
            __syncthreads();
            #pragma unroll
            for (int t2 = 0; t2 < 2; ++t2) {   // QK + P for both tiles
                floatx4 sf[4];
                #pragma unroll
                for (int mb = 0; mb < 4; ++mb)
                    #pragma unroll
                    for (int e = 0; e < 4; ++e) sf[mb][e] = 0.f;
                #pragma unroll
                for (int ks = 0; ks < 2; ++ks) {
                    const int krow = t2 * 64 + w * 16 + r;
                    short8v kf = *(const short8v*)&Ks[krow][((ks * 4 + q) ^ (krow & 7)) * 8];
                    #pragma unroll
                    for (int mb = 0; mb < 4; ++mb)
                        sf[mb] = __builtin_amdgcn_mfma_f32_16x16x32_bf16(qf[mb][ks], kf, sf[mb], 0, 0, 0);
                }
                const bool diag = (s2 + t2 == tt);
                #pragma unroll
                for (int mb = 0; mb < 4; ++mb)
                    #pragma unroll
                    for (int i = 0; i < 4; ++i) {
                        const int rl = mb * 16 + q * 4 + i;
                        float p = (diag && (w * 16 + r > rl)) ? 0.f : __expf(sf[mb][i]);
                        l_part[mb][i] += p;
                        const int c = (w * 2 + (r >> 3)) ^ (rl & 7);
                        Ps[t2][rl][c * 8 + (r & 7)] = f2bf(p);
                    }
            }
            __syncthreads();
            #pragma unroll
            for (int ks = 0; ks < 2; ++ks) {   // PV both s-halves
                const int prow = w * 16 + r;
                const int pcp = ((ks * 4 + q) ^ (prow & 7)) * 8;
                short8v pfA = *(const short8v*)&Ps[0][prow][pcp];
                short8v pfB = *(const short8v*)&Ps[1][prow][pcp];
                #pragma unroll
                for (int nb = 0; nb < 4; ++nb) {
                    const int vrow = nb * 16 + r;
                    const int pcv = (ks * 4 + q) ^ (vrow & 7);
                    short8v vfA = *(const short8v*)&Vt[vrow][pcv * 8];
                    short8v vfB = *(const short8v*)&Vt[vrow][(8 | pcv) * 8];
                    o[nb] = __builtin_amdgcn_mfma_f32_16x16x32_bf16(pfA, vfA, o[nb], 0, 0, 0);
                    o[nb] = __builtin_amdgcn_mfma_f32_16x16x32_bf16(pfB, vfB, o[nb], 0, 0, 0);
                }
            }
        }
        if (s2 < ntiles) {   // odd tail: single tile s2 == tt (diagonal)
            __syncthreads();
            {   // 64 rows x 8 chunks each (2 int4/thread)
                const int sr = tid >> 2, cb = (tid & 3) * 2;
                const short* kp = kbase + (size_t)(s2 * 64 + sr) * RS;
                const short* vp = vbase + (size_t)sr * T_LEN + s2 * 64;
                #pragma unroll
                for (int u = 0; u < 2; ++u) {
                    const int c = cb + u;
                    *(int4*)&Ks[sr][(c ^ (sr & 7)) * 8] = *(const int4*)(kp + c * 8);
                    *(int4*)&Vt[sr][(c ^ (sr & 7)) * 8] = *(const int4*)(vp + c * 8);
                }
            }
            __syncthreads();
            floatx4 sf[4];
            #pragma unroll
            for (int mb = 0; mb < 4; ++mb)
                #pragma unroll
                for (int e = 0; e < 4; ++e) sf[mb][e] = 0.f;
            #pragma unroll
            for (int ks = 0; ks < 2; ++ks) {
                const int krow = w * 16 + r;
                short8v kf = *(const short8v*)&Ks[krow][((ks * 4 + q) ^ (krow & 7)) * 8];
                #pragma unroll
                for (int mb = 0; mb < 4; ++mb)
                    sf[mb] = __builtin_amdgcn_mfma_f32_16x16x32_bf16(qf[mb][ks], kf, sf[mb], 0, 0, 0);
            }
            #pragma unroll
            for (int mb = 0; mb < 4; ++mb)
                #pragma unroll
                for (int i = 0; i < 4; ++i) {
                    const int rl = mb * 16 + q * 4 + i;
                    float p = (w * 16 + r > rl) ? 0.f : __expf(sf[mb][i]);
                    l_part[mb][i] += p;
                    const int c = (w * 2 + (r >> 3)) ^ (rl & 7);
                    Ps[0][rl][c * 8 + (r & 7)] = f2bf(p);
                }
            __syncthreads();
            #pragma unroll
            for (int ks = 0; ks < 2; ++ks) {
                const int prow = w * 16 + r;
                short8v pf = *(const short8v*)&Ps[0][prow][((ks * 4 + q) ^ (prow & 7)) * 8];
                #pragma unroll
                for (int nb = 0; nb < 4; ++nb) {
                    const int vrow = nb * 16 + r;
                    short8v vf = *(const short8v*)&Vt[vrow][(((ks * 4 + q) ^ (vrow & 7))) * 8];
                    o[nb] = __builtin_amdgcn_mfma_f32_16x16x32_bf16(pf, vf, o[nb], 0, 0, 0);
                }
            }
        }

        // ---- epilogue: l reduce (16 r-lanes, then cross-wave), ctx write
        #pragma unroll
        for (int mb = 0; mb < 4; ++mb)
            #pragma unroll
            for (int i = 0; i < 4; ++i) {
                float v = l_part[mb][i];
                v += __shfl_xor(v, 1, 16);
                v += __shfl_xor(v, 2, 16);
                v += __shfl_xor(v, 4, 16);
                v += __shfl_xor(v, 8, 16);
                if (r == 0) Lred[w][mb * 16 + q * 4 + i] = v;
            }
        __syncthreads();
        if (tid < 64) {
            float s = Lred[0][tid] + Lred[1][tid] + Lred[2][tid] + Lred[3][tid];
            Lr[(size_t)bh * T_LEN + t0 + tid] = s;
            Lred[0][tid] = s;
        }
        __syncthreads();
        #pragma unroll
        for (int i = 0; i < 4; ++i) {
            const int tl = w * 16 + q * 4 + i;
            const float inv = 1.0f / Lred[0][tl];
            #pragma unroll
            for (int nb = 0; nb < 4; ++nb)
                ctx[((size_t)(t0 + tl) * BSZ + b) * EMB + h * HDIM + nb * 16 + r] =
                    f2bf(o[nb][i] * inv);
        }
    }
}

// ---------------------------------------------------------------------------
// avg_w[b,t,s] = (1/H) sum_h exp(qk) / l_h[t]. 64x64 output tiles, 2 heads
// per staging round, denominators pre-inverted into Lbuf. Same bf16 inputs +
// MFMA as flash (errors cancel).
// ---------------------------------------------------------------------------
__global__ __launch_bounds__(256) void avg_w_k(const short* __restrict__ qk,
        const float* __restrict__ Lr, float* __restrict__ avg) {
    const int s0 = blockIdx.x * 64, t0 = blockIdx.y * 64, b = blockIdx.z;
    const int tid = threadIdx.x;
    float* outb = avg + (size_t)b * T_LEN * T_LEN;
    if (s0 > t0) {   // fully masked tile: zero-fill (d_out is poisoned)
        const int ty = tid >> 4, tx = tid & 15;
        const float4 z = make_float4(0.f, 0.f, 0.f, 0.f);
        #pragma unroll
        for (int i = 0; i < 4; ++i)
            *(float4*)&outb[(size_t)(t0 + ty * 4 + i) * T_LEN + s0 + tx * 4] = z;
        return;
    }
    __shared__ short Qs[64][128];
    __shared__ short Ks[64][128];
    __shared__ float Lbuf[NHEAD][64];
    const int lane = tid & 63, w = tid >> 6;
    const int q = lane >> 4, r = lane & 15;
    const int srow = tid >> 2, c4 = (tid & 3) * 4;   // 4 chunks of 16B per thread
    const short* qbase = qk + (size_t)b * QK_LD;
    const int RS = BSZ * QK_LD;

    // pre-inverted denominators: 16 heads x 64 t-rows (published by 1st barrier)
    #pragma unroll
    for (int u = 0; u < 4; ++u) {
        const int li = tid * 4 + u;
        const int h = li >> 6, tl = li & 63;
        Lbuf[h][tl] = 0.0625f / Lr[(size_t)(b * NHEAD + h) * T_LEN + t0 + tl];
    }

    floatx4 acc[4];
    #pragma unroll
    for (int nb = 0; nb < 4; ++nb)
        #pragma unroll
        for (int e = 0; e < 4; ++e) acc[nb][e] = 0.f;

    for (int hp = 0; hp < 8; ++hp) {       // head pairs
        const short* qh = qbase + hp * 128;
        const short* kh = qbase + EMB + hp * 128;
        __syncthreads();
        #pragma unroll
        for (int u = 0; u < 4; ++u) {
            const int c = c4 + u;                              // chunk 0..15
            const int pc = (c & 8) | ((c & 7) ^ (srow & 7));   // swizzle within head
            *(int4*)&Qs[srow][pc * 8] =
                *(const int4*)(qh + (size_t)(t0 + srow) * RS + c * 8);
            *(int4*)&Ks[srow][pc * 8] =
                *(const int4*)(kh + (size_t)(s0 + srow) * RS + c * 8);
        }
        __syncthreads();

        #pragma unroll
        for (int hs = 0; hs < 2; ++hs) {
            const int h = hp * 2 + hs;
            floatx4 sf[4];
            #pragma unroll
            for (int nb = 0; nb < 4; ++nb)
                #pragma unroll
                for (int e = 0; e < 4; ++e) sf[nb][e] = 0.f;
            #pragma unroll
            for (int ks = 0; ks < 2; ++ks) {
                const int qrow = w * 16 + r;
                short8v qfr = *(const short8v*)
                    &Qs[qrow][((hs * 8) | ((ks * 4 + q) ^ (qrow & 7))) * 8];
                #pragma unroll
                for (int nb = 0; nb < 4; ++nb) {
                    const int krow = nb * 16 + r;
                    short8v kfr = *(const short8v*)
                        &Ks[krow][((hs * 8) | ((ks * 4 + q) ^ (krow & 7))) * 8];
                    sf[nb] = __builtin_amdgcn_mfma_f32_16x16x32_bf16(qfr, kfr, sf[nb], 0, 0, 0);
                }
            }
            #pragma unroll
            for (int i = 0; i < 4; ++i) {
                const int tl = w * 16 + q * 4 + i;
                const float inv = Lbuf[h][tl];
                #pragma unroll
                for (int nb = 0; nb < 4; ++nb) {
                    float e = (s0 == t0 && (nb * 16 + r > tl))
                              ? 0.f : __expf(sf[nb][i]) * inv;
                    acc[nb][i] += e;
                }
            }
        }
    }

    #pragma unroll
    for (int i = 0; i < 4; ++i) {
        const int t = t0 + w * 16 + q * 4 + i;
        #pragma unroll
        for (int nb = 0; nb < 4; ++nb)
            outb[(size_t)t * T_LEN + s0 + nb * 16 + r] = acc[nb][i];
    }
}

// ---------------------------------------------------------------------------
// Workspace (32.3 MiB, under the 40.3 proven-safe layout): query is read
// fp32 directly by gemm1 (a_fp32 path), so no qb buffer; ctx gets its own.
// ---------------------------------------------------------------------------
extern "C" void kernel_launch(void* const* d_in, const int* in_sizes, int n_in,
                              void* d_out, int out_size, void* d_ws, size_t ws_size,
                              hipStream_t stream) {
    (void)in_sizes; (void)n_in; (void)out_size; (void)ws_size;
    const float* query = (const float*)d_in[0];
    const float* w_in  = (const float*)d_in[1];
    const float* b_in  = (const float*)d_in[2];
    const float* w_out = (const float*)d_in[3];
    const float* b_out = (const float*)d_in[4];

    float* out = (float*)d_out;                           // [T,B,E] fp32
    float* avg = out + (size_t)T_LEN * BSZ * EMB;         // [B,T,T] fp32

    short* ws     = (short*)d_ws;
    short* wb_in  = ws;                                   // w_in bf16  [3072,1024]  6 MB
    short* wb_out = wb_in  + (size_t)3072 * 1024;         // w_out bf16 [1024,1024]  2 MB
    short* qkb    = wb_out + (size_t)1024 * 1024;         // q,k bf16   [4096,2048] 16 MB
    short* vTb    = qkb    + (size_t)4096 * 2048;         // V^T bf16   [B*E, T]     8 MB
    short* ctxb   = vTb    + (size_t)BSZ * EMB * T_LEN;   // ctx bf16   [4096,1024]  8 MB
    float* Lr     = (float*)(ctxb + (size_t)4096 * 1024); // [B*H, T]              256 KB

    f32_to_bf16_k<<<3072, 256, 0, stream>>>(w_in,  wb_in,  3072 * 1024);
    f32_to_bf16_k<<<1024, 256, 0, stream>>>(w_out, wb_out, 1024 * 1024);

    // QKV projection: A = query fp32 (staged-convert), q,k -> qkb, v -> vTb
    gemm_bf16<<<dim3(24, 32), 256, 0, stream>>>(query, wb_in, b_in, qkb, vTb,
                                                4096, 3072, 1024, EMB, 1, QK_LD, 1);
    flash_fwd<<<dim3(32, 16), 256, 0, stream>>>(qkb, vTb, ctxb, Lr);
    avg_w_k<<<dim3(32, 32, 2), 256, 0, stream>>>(qkb, Lr, avg);
    gemm_bf16<<<dim3(8, 32), 256, 0, stream>>>(ctxb, wb_out, b_out, out, (short*)0,
                                               4096, 1024, 1024, 0, 0, 1024, 0);
}

// Round 9
// 251.627 us; speedup vs baseline: 1.4123x; 1.0322x over previous
//
#include <hip/hip_runtime.h>
#include <math.h>

#define T_LEN 2048
#define BSZ 2
#define EMB 1024
#define NHEAD 16
#define HDIM 64
#define QK_LD 2048   // q,k packed [T*B, 2E]

typedef __attribute__((ext_vector_type(8))) short short8v;   // 8 bf16 (4 VGPRs)
typedef __attribute__((ext_vector_type(4))) float floatx4;   // MFMA C/D

__device__ __forceinline__ short f2bf(float f) {
    unsigned u = __float_as_uint(f);
    u += 0x7fffu + ((u >> 16) & 1u);   // RNE
    return (short)(u >> 16);
}

// ---------------------------------------------------------------------------
__global__ __launch_bounds__(256) void f32_to_bf16_k(const float* __restrict__ src,
                                                     short* __restrict__ dst, int n) {
    int i = (blockIdx.x * 256 + threadIdx.x) * 4;
    if (i >= n) return;
    float4 v = *(const float4*)(src + i);
    short4 o = make_short4(f2bf(v.x), f2bf(v.y), f2bf(v.z), f2bf(v.w));
    *(short4*)(dst + i) = o;
}

// ---------------------------------------------------------------------------
// C = A[M,K]*B[N,K]^T + bias; cols < scale_cols get *0.125 (q scale).
// a_fp32: A is fp32, converted to bf16 during LDS staging.
// GRID IS (mtile, ntile): linear%8 = mtile%8, so each XCD keeps its 4
// A-slabs resident in L2 (R8 counter: 68.7 MB FETCH = 3x A-overfetch with
// the n-fastest grid). If vTout != 0, cols >= 2*EMB are written TRANSPOSED
// to vT[b][e][t]. bf16 MFMA 16x16x32, 128x128 tile, BK=32, 4 waves.
// ---------------------------------------------------------------------------
__global__ __launch_bounds__(256) void gemm_bf16(const void* __restrict__ Ain,
        const short* __restrict__ B, const float* __restrict__ bias,
        void* __restrict__ Cout, short* __restrict__ vTout,
        int M, int N, int K, int scale_cols, int out_bf16, int ldC, int a_fp32) {
    __shared__ short As[128][32];
    __shared__ short Bs[128][32];
    const int tid = threadIdx.x;
    const int m0 = blockIdx.x * 128, n0 = blockIdx.y * 128;   // x=mtile (XCD locality)
    const int lane = tid & 63, w = tid >> 6;
    const int q = lane >> 4, r = lane & 15;
    const int wr = w >> 1, wc = w & 1;
    const int srow = tid >> 2, sc4 = tid & 3;
    const int sp = (sc4 ^ ((srow >> 1) & 3)) * 8;

    const short* Brow0 = B + (size_t)(n0 + srow) * K + sc4 * 8;
    const short* Brow1 = Brow0 + (size_t)64 * K;

    floatx4 acc[4][4];
    #pragma unroll
    for (int a = 0; a < 4; ++a)
        #pragma unroll
        for (int b2 = 0; b2 < 4; ++b2)
            #pragma unroll
            for (int e = 0; e < 4; ++e) acc[a][b2][e] = 0.f;

    for (int k0 = 0; k0 < K; k0 += 32) {
        int4 a0, a1;
        if (a_fp32) {
            const float* Af = (const float*)Ain;
            const float* p0 = Af + (size_t)(m0 + srow) * K + sc4 * 8 + k0;
            const float* p1 = p0 + (size_t)64 * K;
            float4 f00 = *(const float4*)p0, f01 = *(const float4*)(p0 + 4);
            float4 f10 = *(const float4*)p1, f11 = *(const float4*)(p1 + 4);
            short4 s00 = make_short4(f2bf(f00.x), f2bf(f00.y), f2bf(f00.z), f2bf(f00.w));
            short4 s01 = make_short4(f2bf(f01.x), f2bf(f01.y), f2bf(f01.z), f2bf(f01.w));
            short4 s10 = make_short4(f2bf(f10.x), f2bf(f10.y), f2bf(f10.z), f2bf(f10.w));
            short4 s11 = make_short4(f2bf(f11.x), f2bf(f11.y), f2bf(f11.z), f2bf(f11.w));
            a0 = make_int4(*(int*)&s00.x, *(int*)&s00.z, *(int*)&s01.x, *(int*)&s01.z);
            a1 = make_int4(*(int*)&s10.x, *(int*)&s10.z, *(int*)&s11.x, *(int*)&s11.z);
        } else {
            const short* As8 = (const short*)Ain + (size_t)(m0 + srow) * K + sc4 * 8 + k0;
            a0 = *(const int4*)As8;
            a1 = *(const int4*)(As8 + (size_t)64 * K);
        }
        int4 b0 = *(const int4*)(Brow0 + k0);
        int4 b1 = *(const int4*)(Brow1 + k0);
        __syncthreads();
        *(int4*)&As[srow][sp] = a0;
        *(int4*)&As[64 + srow][sp] = a1;
        *(int4*)&Bs[srow][sp] = b0;
        *(int4*)&Bs[64 + srow][sp] = b1;
        __syncthreads();
        short8v af[4], bfr[4];
        #pragma unroll
        for (int mb = 0; mb < 4; ++mb) {
            int row = wr * 64 + mb * 16 + r;
            af[mb] = *(const short8v*)&As[row][(q ^ ((row >> 1) & 3)) * 8];
        }
        #pragma unroll
        for (int nb = 0; nb < 4; ++nb) {
            int row = wc * 64 + nb * 16 + r;
            bfr[nb] = *(const short8v*)&Bs[row][(q ^ ((row >> 1) & 3)) * 8];
        }
        #pragma unroll
        for (int mb = 0; mb < 4; ++mb)
            #pragma unroll
            for (int nb = 0; nb < 4; ++nb)
                acc[mb][nb] = __builtin_amdgcn_mfma_f32_16x16x32_bf16(af[mb], bfr[nb], acc[mb][nb], 0, 0, 0);
    }

    #pragma unroll
    for (int nb = 0; nb < 4; ++nb) {
        const int col = n0 + wc * 64 + nb * 16 + r;
        const float bi = bias[col];
        const float sc = (col < scale_cols) ? 0.125f : 1.0f;
        if (vTout && col >= 2 * EMB) {
            const int e = col - 2 * EMB;
            #pragma unroll
            for (int mb = 0; mb < 4; ++mb) {
                const int base = m0 + wr * 64 + mb * 16 + q * 4;   // multiple of 4
                float v0 = acc[mb][nb][0] + bi, v1 = acc[mb][nb][1] + bi;
                float v2 = acc[mb][nb][2] + bi, v3 = acc[mb][nb][3] + bi;
                // rows (t*2+b): i=0,2 -> b=0 t,t+1 ; i=1,3 -> b=1 t,t+1
                unsigned lo = (unsigned short)f2bf(v0) | ((unsigned)(unsigned short)f2bf(v2) << 16);
                unsigned hi = (unsigned short)f2bf(v1) | ((unsigned)(unsigned short)f2bf(v3) << 16);
                *(unsigned*)&vTout[(size_t)e * T_LEN + (base >> 1)]         = lo;
                *(unsigned*)&vTout[((size_t)EMB + e) * T_LEN + (base >> 1)] = hi;
            }
        } else {
            #pragma unroll
            for (int mb = 0; mb < 4; ++mb)
                #pragma unroll
                for (int i = 0; i < 4; ++i) {
                    const int rowg = m0 + wr * 64 + mb * 16 + q * 4 + i;
                    const float v = (acc[mb][nb][i] + bi) * sc;
                    if (out_bf16) ((short*)Cout)[(size_t)rowg * ldC + col] = f2bf(v);
                    else          ((float*)Cout)[(size_t)rowg * ldC + col] = v;
                }
        }
    }
}

// ---------------------------------------------------------------------------
// Flash causal attention. Triangle pairing (ttile=pairi then 31-pairi, 33
// s-tiles per block, no atomics). GRID IS (bh, pairi): linear%8 = bh%8 so
// each XCD hosts only 4 bh values -> K/V working set 2 MB fits per-XCD L2.
// 2 s-tiles per staging round, P double-buffered, no online max.
// ---------------------------------------------------------------------------
__global__ __launch_bounds__(256) void flash_fwd(const short* __restrict__ qk,
        const short* __restrict__ vT, short* __restrict__ ctx,
        float* __restrict__ Lr) {
    __shared__ short Ks[128][64];       // 2 s-tiles of K
    __shared__ short Vt[64][128];       // V^T: [d][2 s-tiles]
    __shared__ short Ps[2][64][64];     // P dbuf; Ps[0] doubles as Q staging
    __shared__ float Lred[4][64];
    const int tid = threadIdx.x;
    const int bh = blockIdx.x;          // XCD locality: linear%8 = bh%8
    const int pairi = blockIdx.y;       // 0..15
    const int b = bh >> 4, h = bh & 15;
    const int lane = tid & 63, w = tid >> 6;
    const int q = lane >> 4, r = lane & 15;
    const int RS = BSZ * QK_LD;

    const short* qbase = qk + (size_t)b * QK_LD + h * HDIM;
    const short* kbase = qbase + EMB;
    const short* vbase = vT + ((size_t)b * EMB + h * HDIM) * T_LEN;

    for (int pass = 0; pass < 2; ++pass) {
        const int tt = pass ? (31 - pairi) : pairi;
        const int t0 = tt << 6;
        __syncthreads();   // prior pass's Ps/Lred reads done
        {   // stage Q into Ps[0]
            const int sr = tid >> 3, c8 = tid & 7;
            *(int4*)&Ps[0][sr][(c8 ^ (sr & 7)) * 8] =
                *(const int4*)(qbase + (size_t)(t0 + sr) * RS + c8 * 8);
            *(int4*)&Ps[0][sr + 32][(c8 ^ ((sr + 32) & 7)) * 8] =
                *(const int4*)(qbase + (size_t)(t0 + sr + 32) * RS + c8 * 8);
        }
        __syncthreads();
        short8v qf[4][2];
        #pragma unroll
        for (int mb = 0; mb < 4; ++mb)
            #pragma unroll
            for (int ks = 0; ks < 2; ++ks) {
                int row = mb * 16 + r;
                qf[mb][ks] = *(const short8v*)&Ps[0][row][((ks * 4 + q) ^ (row & 7)) * 8];
            }

        float l_part[4][4];
        floatx4 o[4];
        #pragma unroll
        for (int mb = 0; mb < 4; ++mb)
            #pragma unroll
            for (int i = 0; i < 4; ++i) l_part[mb][i] = 0.f;
        #pragma unroll
        for (int nb = 0; nb < 4; ++nb)
            #pragma unroll
            for (int e = 0; e < 4; ++e) o[nb][e] = 0.f;

        const int ntiles = tt + 1;
        int s2 = 0;
        for (; s2 + 2 <= ntiles; s2 += 2) {   // paired rounds: 128 s per stage
            __syncthreads();
            {   // K: 128 rows x 8 chunks (4 int4/thread)
                const int sr = tid >> 1, cb = (tid & 1) * 4;
                const short* kp = kbase + (size_t)(s2 * 64 + sr) * RS;
                #pragma unroll
                for (int u = 0; u < 4; ++u) {
                    const int c = cb + u;
                    *(int4*)&Ks[sr][(c ^ (sr & 7)) * 8] = *(const int4*)(kp + c * 8);
                }
                // V^T: 64 rows x 16 chunks (4 int4/thread)
                const int vr = tid >> 2, vb0 = (tid & 3) * 4;
                const short* vp = vbase + (size_t)vr * T_LEN + s2 * 64;
                #pragma unroll
                for (int u = 0; u < 4; ++u) {
                    const int c = vb0 + u;
                    const int pc = (c & 8) | ((c & 7) ^ (vr & 7));
                    *(int4*)&Vt[vr][pc * 8] = *(const int4*)(vp + c * 8);
                }
            }
            __syncthreads();
            #pragma unroll
            for (int t2 = 0; t2 < 2; ++t2) {   // QK + P for both tiles
                floatx4 sf[4];
                #pragma unroll
                for (int mb = 0; mb < 4; ++mb)
                    #pragma unroll
                    for (int e = 0; e < 4; ++e) sf[mb][e] = 0.f;
                #pragma unroll
                for (int ks = 0; ks < 2; ++ks) {
                    const int krow = t2 * 64 + w * 16 + r;
                    short8v kf = *(const short8v*)&Ks[krow][((ks * 4 + q) ^ (krow & 7)) * 8];
                    #pragma unroll
                    for (int mb = 0; mb < 4; ++mb)
                        sf[mb] = __builtin_amdgcn_mfma_f32_16x16x32_bf16(qf[mb][ks], kf, sf[mb], 0, 0, 0);
                }
                const bool diag = (s2 + t2 == tt);
                #pragma unroll
                for (int mb = 0; mb < 4; ++mb)
                    #pragma unroll
                    for (int i = 0; i < 4; ++i) {
                        const int rl = mb * 16 + q * 4 + i;
                        float p = (diag && (w * 16 + r > rl)) ? 0.f : __expf(sf[mb][i]);
                        l_part[mb][i] += p;
                        const int c = (w * 2 + (r >> 3)) ^ (rl & 7);
                        Ps[t2][rl][c * 8 + (r & 7)] = f2bf(p);
                    }
            }
            __syncthreads();
            #pragma unroll
            for (int ks = 0; ks < 2; ++ks) {   // PV both s-halves
                const int prow = w * 16 + r;
                const int pcp = ((ks * 4 + q) ^ (prow & 7)) * 8;
                short8v pfA = *(const short8v*)&Ps[0][prow][pcp];
                short8v pfB = *(const short8v*)&Ps[1][prow][pcp];
                #pragma unroll
                for (int nb = 0; nb < 4; ++nb) {
                    const int vrow = nb * 16 + r;
                    const int pcv = (ks * 4 + q) ^ (vrow & 7);
                    short8v vfA = *(const short8v*)&Vt[vrow][pcv * 8];
                    short8v vfB = *(const short8v*)&Vt[vrow][(8 | pcv) * 8];
                    o[nb] = __builtin_amdgcn_mfma_f32_16x16x32_bf16(pfA, vfA, o[nb], 0, 0, 0);
                    o[nb] = __builtin_amdgcn_mfma_f32_16x16x32_bf16(pfB, vfB, o[nb], 0, 0, 0);
                }
            }
        }
        if (s2 < ntiles) {   // odd tail: single tile s2 == tt (diagonal)
            __syncthreads();
            {   // 64 rows x 8 chunks each (2 int4/thread)
                const int sr = tid >> 2, cb = (tid & 3) * 2;
                const short* kp = kbase + (size_t)(s2 * 64 + sr) * RS;
                const short* vp = vbase + (size_t)sr * T_LEN + s2 * 64;
                #pragma unroll
                for (int u = 0; u < 2; ++u) {
                    const int c = cb + u;
                    *(int4*)&Ks[sr][(c ^ (sr & 7)) * 8] = *(const int4*)(kp + c * 8);
                    *(int4*)&Vt[sr][(c ^ (sr & 7)) * 8] = *(const int4*)(vp + c * 8);
                }
            }
            __syncthreads();
            floatx4 sf[4];
            #pragma unroll
            for (int mb = 0; mb < 4; ++mb)
                #pragma unroll
                for (int e = 0; e < 4; ++e) sf[mb][e] = 0.f;
            #pragma unroll
            for (int ks = 0; ks < 2; ++ks) {
                const int krow = w * 16 + r;
                short8v kf = *(const short8v*)&Ks[krow][((ks * 4 + q) ^ (krow & 7)) * 8];
                #pragma unroll
                for (int mb = 0; mb < 4; ++mb)
                    sf[mb] = __builtin_amdgcn_mfma_f32_16x16x32_bf16(qf[mb][ks], kf, sf[mb], 0, 0, 0);
            }
            #pragma unroll
            for (int mb = 0; mb < 4; ++mb)
                #pragma unroll
                for (int i = 0; i < 4; ++i) {
                    const int rl = mb * 16 + q * 4 + i;
                    float p = (w * 16 + r > rl) ? 0.f : __expf(sf[mb][i]);
                    l_part[mb][i] += p;
                    const int c = (w * 2 + (r >> 3)) ^ (rl & 7);
                    Ps[0][rl][c * 8 + (r & 7)] = f2bf(p);
                }
            __syncthreads();
            #pragma unroll
            for (int ks = 0; ks < 2; ++ks) {
                const int prow = w * 16 + r;
                short8v pf = *(const short8v*)&Ps[0][prow][((ks * 4 + q) ^ (prow & 7)) * 8];
                #pragma unroll
                for (int nb = 0; nb < 4; ++nb) {
                    const int vrow = nb * 16 + r;
                    short8v vf = *(const short8v*)&Vt[vrow][(((ks * 4 + q) ^ (vrow & 7))) * 8];
                    o[nb] = __builtin_amdgcn_mfma_f32_16x16x32_bf16(pf, vf, o[nb], 0, 0, 0);
                }
            }
        }

        // ---- epilogue: l reduce (16 r-lanes, then cross-wave), ctx write
        #pragma unroll
        for (int mb = 0; mb < 4; ++mb)
            #pragma unroll
            for (int i = 0; i < 4; ++i) {
                float v = l_part[mb][i];
                v += __shfl_xor(v, 1, 16);
                v += __shfl_xor(v, 2, 16);
                v += __shfl_xor(v, 4, 16);
                v += __shfl_xor(v, 8, 16);
                if (r == 0) Lred[w][mb * 16 + q * 4 + i] = v;
            }
        __syncthreads();
        if (tid < 64) {
            float s = Lred[0][tid] + Lred[1][tid] + Lred[2][tid] + Lred[3][tid];
            Lr[(size_t)bh * T_LEN + t0 + tid] = s;
            Lred[0][tid] = s;
        }
        __syncthreads();
        #pragma unroll
        for (int i = 0; i < 4; ++i) {
            const int tl = w * 16 + q * 4 + i;
            const float inv = 1.0f / Lred[0][tl];
            #pragma unroll
            for (int nb = 0; nb < 4; ++nb)
                ctx[((size_t)(t0 + tl) * BSZ + b) * EMB + h * HDIM + nb * 16 + r] =
                    f2bf(o[nb][i] * inv);
        }
    }
}

// ---------------------------------------------------------------------------
// avg_w[b,t,s] = (1/H) sum_h exp(qk) / l_h[t]. 64x64 output tiles, 2 heads
// per staging round, denominators pre-inverted into Lbuf. Same bf16 inputs +
// MFMA as flash (errors cancel).
// ---------------------------------------------------------------------------
__global__ __launch_bounds__(256) void avg_w_k(const short* __restrict__ qk,
        const float* __restrict__ Lr, float* __restrict__ avg) {
    const int s0 = blockIdx.x * 64, t0 = blockIdx.y * 64, b = blockIdx.z;
    const int tid = threadIdx.x;
    float* outb = avg + (size_t)b * T_LEN * T_LEN;
    if (s0 > t0) {   // fully masked tile: zero-fill (d_out is poisoned)
        const int ty = tid >> 4, tx = tid & 15;
        const float4 z = make_float4(0.f, 0.f, 0.f, 0.f);
        #pragma unroll
        for (int i = 0; i < 4; ++i)
            *(float4*)&outb[(size_t)(t0 + ty * 4 + i) * T_LEN + s0 + tx * 4] = z;
        return;
    }
    __shared__ short Qs[64][128];
    __shared__ short Ks[64][128];
    __shared__ float Lbuf[NHEAD][64];
    const int lane = tid & 63, w = tid >> 6;
    const int q = lane >> 4, r = lane & 15;
    const int srow = tid >> 2, c4 = (tid & 3) * 4;   // 4 chunks of 16B per thread
    const short* qbase = qk + (size_t)b * QK_LD;
    const int RS = BSZ * QK_LD;

    // pre-inverted denominators: 16 heads x 64 t-rows (published by 1st barrier)
    #pragma unroll
    for (int u = 0; u < 4; ++u) {
        const int li = tid * 4 + u;
        const int h = li >> 6, tl = li & 63;
        Lbuf[h][tl] = 0.0625f / Lr[(size_t)(b * NHEAD + h) * T_LEN + t0 + tl];
    }

    floatx4 acc[4];
    #pragma unroll
    for (int nb = 0; nb < 4; ++nb)
        #pragma unroll
        for (int e = 0; e < 4; ++e) acc[nb][e] = 0.f;

    for (int hp = 0; hp < 8; ++hp) {       // head pairs
        const short* qh = qbase + hp * 128;
        const short* kh = qbase + EMB + hp * 128;
        __syncthreads();
        #pragma unroll
        for (int u = 0; u < 4; ++u) {
            const int c = c4 + u;                              // chunk 0..15
            const int pc = (c & 8) | ((c & 7) ^ (srow & 7));   // swizzle within head
            *(int4*)&Qs[srow][pc * 8] =
                *(const int4*)(qh + (size_t)(t0 + srow) * RS + c * 8);
            *(int4*)&Ks[srow][pc * 8] =
                *(const int4*)(kh + (size_t)(s0 + srow) * RS + c * 8);
        }
        __syncthreads();

        #pragma unroll
        for (int hs = 0; hs < 2; ++hs) {
            const int h = hp * 2 + hs;
            floatx4 sf[4];
            #pragma unroll
            for (int nb = 0; nb < 4; ++nb)
                #pragma unroll
                for (int e = 0; e < 4; ++e) sf[nb][e] = 0.f;
            #pragma unroll
            for (int ks = 0; ks < 2; ++ks) {
                const int qrow = w * 16 + r;
                short8v qfr = *(const short8v*)
                    &Qs[qrow][((hs * 8) | ((ks * 4 + q) ^ (qrow & 7))) * 8];
                #pragma unroll
                for (int nb = 0; nb < 4; ++nb) {
                    const int krow = nb * 16 + r;
                    short8v kfr = *(const short8v*)
                        &Ks[krow][((hs * 8) | ((ks * 4 + q) ^ (krow & 7))) * 8];
                    sf[nb] = __builtin_amdgcn_mfma_f32_16x16x32_bf16(qfr, kfr, sf[nb], 0, 0, 0);
                }
            }
            #pragma unroll
            for (int i = 0; i < 4; ++i) {
                const int tl = w * 16 + q * 4 + i;
                const float inv = Lbuf[h][tl];
                #pragma unroll
                for (int nb = 0; nb < 4; ++nb) {
                    float e = (s0 == t0 && (nb * 16 + r > tl))
                              ? 0.f : __expf(sf[nb][i]) * inv;
                    acc[nb][i] += e;
                }
            }
        }
    }

    #pragma unroll
    for (int i = 0; i < 4; ++i) {
        const int t = t0 + w * 16 + q * 4 + i;
        #pragma unroll
        for (int nb = 0; nb < 4; ++nb)
            outb[(size_t)t * T_LEN + s0 + nb * 16 + r] = acc[nb][i];
    }
}

// ---------------------------------------------------------------------------
// Workspace (32.3 MiB, under the 40.3 proven-safe layout).
// ---------------------------------------------------------------------------
extern "C" void kernel_launch(void* const* d_in, const int* in_sizes, int n_in,
                              void* d_out, int out_size, void* d_ws, size_t ws_size,
                              hipStream_t stream) {
    (void)in_sizes; (void)n_in; (void)out_size; (void)ws_size;
    const float* query = (const float*)d_in[0];
    const float* w_in  = (const float*)d_in[1];
    const float* b_in  = (const float*)d_in[2];
    const float* w_out = (const float*)d_in[3];
    const float* b_out = (const float*)d_in[4];

    float* out = (float*)d_out;                           // [T,B,E] fp32
    float* avg = out + (size_t)T_LEN * BSZ * EMB;         // [B,T,T] fp32

    short* ws     = (short*)d_ws;
    short* wb_in  = ws;                                   // w_in bf16  [3072,1024]  6 MB
    short* wb_out = wb_in  + (size_t)3072 * 1024;         // w_out bf16 [1024,1024]  2 MB
    short* qkb    = wb_out + (size_t)1024 * 1024;         // q,k bf16   [4096,2048] 16 MB
    short* vTb    = qkb    + (size_t)4096 * 2048;         // V^T bf16   [B*E, T]     8 MB
    short* ctxb   = vTb    + (size_t)BSZ * EMB * T_LEN;   // ctx bf16   [4096,1024]  8 MB
    float* Lr     = (float*)(ctxb + (size_t)4096 * 1024); // [B*H, T]              256 KB

    f32_to_bf16_k<<<3072, 256, 0, stream>>>(w_in,  wb_in,  3072 * 1024);
    f32_to_bf16_k<<<1024, 256, 0, stream>>>(w_out, wb_out, 1024 * 1024);

    // QKV projection: A = query fp32 (staged-convert), q,k -> qkb, v -> vTb
    // grid x=mtile (32), y=ntile (24): per-XCD A-slab residency
    gemm_bf16<<<dim3(32, 24), 256, 0, stream>>>(query, wb_in, b_in, qkb, vTb,
                                                4096, 3072, 1024, EMB, 1, QK_LD, 1);
    flash_fwd<<<dim3(32, 16), 256, 0, stream>>>(qkb, vTb, ctxb, Lr);
    avg_w_k<<<dim3(32, 32, 2), 256, 0, stream>>>(qkb, Lr, avg);
    gemm_bf16<<<dim3(32, 8), 256, 0, stream>>>(ctxb, wb_out, b_out, out, (short*)0,
                                               4096, 1024, 1024, 0, 0, 1024, 0);
}